// Round 8
// baseline (810.444 us; speedup 1.0000x reference)
//
#include <hip/hip_runtime.h>
#include <hip/hip_bf16.h>

#define D   128
#define DM  256
#define DI  512
#define HH  512
#define KNN 10
#define NN  64
#define BQ  4096
#define BS  128
#define BM2 (BQ + BS)        // 4224 batched se rows
#define G2  1024             // live LSTM gate rows (4 gates x 256 live units)
#define GK  256              // LSTM GEMM K
#define NSYM 200000
#define NB  256              // mega-kernel grid (== CU count, all co-resident)

__device__ __forceinline__ float sigmoidf_(float x) {
    return 1.f / (1.f + __expf(-x));
}
__device__ __forceinline__ float tanh_fast(float x) {
    x = fminf(fmaxf(x, -20.f), 20.f);
    float e = __expf(2.f * x);
    return (e - 1.f) / (e + 1.f);
}
__device__ __forceinline__ ushort f2bf(float x) {
    union { float f; unsigned u; } v; v.f = x;
    unsigned r = (v.u + 0x7fffu + ((v.u >> 16) & 1u)) >> 16;  // RNE
    return (ushort)r;
}

typedef __bf16  bf16x8  __attribute__((ext_vector_type(8)));
typedef float   floatx4 __attribute__((ext_vector_type(4)));

// ---- device-scope sense-reversing barrier (all NB blocks co-resident) ----
__device__ __forceinline__ void gsync(unsigned* bar, unsigned* gen)
{
    __threadfence();          // device-scope release of this block's writes
    __syncthreads();
    if (threadIdx.x == 0) {
        unsigned g = __hip_atomic_load(gen, __ATOMIC_RELAXED, __HIP_MEMORY_SCOPE_AGENT);
        unsigned old = __hip_atomic_fetch_add(bar, 1u, __ATOMIC_ACQ_REL, __HIP_MEMORY_SCOPE_AGENT);
        if (old == NB - 1) {
            __hip_atomic_store(bar, 0u, __ATOMIC_RELAXED, __HIP_MEMORY_SCOPE_AGENT);
            __hip_atomic_store(gen, g + 1u, __ATOMIC_RELEASE, __HIP_MEMORY_SCOPE_AGENT);
        } else {
            while (__hip_atomic_load(gen, __ATOMIC_ACQUIRE, __HIP_MEMORY_SCOPE_AGENT) == g)
                __builtin_amdgcn_s_sleep(8);
        }
    }
    __syncthreads();
}

// ---------------- prologue: emb norms + weight conversion + bsumP + barrier init ----------------
__global__ __launch_bounds__(256) void prep_kernel(
    const float* __restrict__ emb, float* __restrict__ norms,
    const float* __restrict__ W_ih, const float* __restrict__ W_hh,
    const float* __restrict__ b_ih, const float* __restrict__ b_hh,
    const float* __restrict__ se_w1, const float* __restrict__ se_w2,
    ushort* __restrict__ wih_bf, ushort* __restrict__ whh_bf,
    float* __restrict__ bsumP, ushort* __restrict__ w1_bf,
    ushort* __restrict__ w2_bf, unsigned* __restrict__ bar,
    unsigned* __restrict__ gen)
{
    int bid = blockIdx.x;
    int tid = threadIdx.x;
    if (bid < 50000) {
        int wave = tid >> 6, lane = tid & 63;
        int row = bid * 4 + wave;
        float2 v = *(const float2*)&emb[(size_t)row * D + lane * 2];
        float s = v.x * v.x + v.y * v.y;
        #pragma unroll
        for (int off = 32; off; off >>= 1) s += __shfl_xor(s, off);
        if (lane == 0) norms[row] = sqrtf(s);
    } else if (bid < 50000 + G2) {
        int n = bid - 50000;
        int bn = n >> 7, r = n & 127;
        int half = (r >> 6) & 1, j = (r >> 4) & 3, l = r & 15;
        int u = bn * 32 + half * 16 + l;
        int oldrow = j * 512 + u;
        wih_bf[n * 256 + tid] = f2bf(W_ih[(size_t)oldrow * DM + tid]);
        whh_bf[n * 256 + tid] = f2bf(W_hh[(size_t)oldrow * HH + tid]);
        if (tid == 0) bsumP[n] = b_ih[oldrow] + b_hh[oldrow];
        if (n == 0 && tid == 1) { *bar = 0u; *gen = 0u; }   // barrier init (ws is poisoned)
    } else {
        int idx = (bid - 50000 - G2) * 256 + tid;
        w1_bf[idx] = f2bf(se_w1[idx]);
        w2_bf[idx] = f2bf(se_w2[idx]);
    }
}

// ---------------- neighbor encoder (merged q+s): register fragments ----------------
__global__ __launch_bounds__(256) void ne_kernel(
    const int* __restrict__ q_l, const int* __restrict__ q_r,
    const int* __restrict__ q_ids,
    const int* __restrict__ s_l, const int* __restrict__ s_r,
    const int* __restrict__ s_ids,
    const float* __restrict__ emb, const float* __restrict__ norms,
    float* __restrict__ catm_out)
{
    int bid = blockIdx.x;
    const int *conn_l, *conn_r, *ids;
    int row;
    if (bid < BQ * 2) { conn_l = q_l; conn_r = q_r; ids = q_ids; row = bid >> 1; }
    else { conn_l = s_l; conn_r = s_r; ids = s_ids; row = (bid - BQ * 2) >> 1; }
    int side = bid & 1;
    const int* conn = (side ? conn_r : conn_l) + (size_t)row * NN * 2;
    int cid = ids[row * 2 + side];

    __shared__ int   connb[NN * 2];
    __shared__ float sim[NN];
    __shared__ int   selr[KNN], sele[KNN];

    int tid = threadIdx.x;
    int wave = tid >> 6, lane = tid & 63;
    int grp = lane >> 4, l16 = lane & 15;

    if (tid < NN * 2) connb[tid] = conn[tid];
    const float* cp = &emb[(size_t)cid * D + l16 * 8];
    float4 c4a = *(const float4*)cp;
    float4 c4b = *(const float4*)(cp + 4);
    float cnorm = fmaxf(norms[cid], 1e-8f);
    __syncthreads();

    float4 ea[4], eb[4];
    #pragma unroll
    for (int b = 0; b < 4; b++) {
        int j = wave * 16 + b * 4 + grp;
        int eid = connb[j * 2 + 1];
        const float* ep = &emb[(size_t)eid * D + l16 * 8];
        ea[b] = *(const float4*)ep;
        eb[b] = *(const float4*)(ep + 4);
    }
    #pragma unroll
    for (int b = 0; b < 4; b++) {
        int j = wave * 16 + b * 4 + grp;
        float dot = c4a.x * ea[b].x + c4a.y * ea[b].y + c4a.z * ea[b].z + c4a.w * ea[b].w
                  + c4b.x * eb[b].x + c4b.y * eb[b].y + c4b.z * eb[b].z + c4b.w * eb[b].w;
        #pragma unroll
        for (int off = 8; off; off >>= 1) dot += __shfl_xor(dot, off);
        if (l16 == 0) sim[j] = dot / cnorm;
    }
    __syncthreads();
    if (tid < NN) sim[tid] = sim[tid] / fmaxf(norms[connb[tid * 2 + 1]], 1e-8f);
    __syncthreads();

    // top-10 by (max value, min index) — matches jax.lax.top_k tie-breaking
    if (wave == 0) {
        float s = sim[lane];
        int id = lane;
        for (int k = 0; k < KNN; k++) {
            float bs = s; int bi = id;
            #pragma unroll
            for (int off = 32; off; off >>= 1) {
                float os = __shfl_xor(bs, off);
                int   oi = __shfl_xor(bi, off);
                if (os > bs || (os == bs && oi < bi)) { bs = os; bi = oi; }
            }
            if (lane == 0) { selr[k] = connb[bi * 2]; sele[k] = connb[bi * 2 + 1]; }
            if (id == bi) s = -__builtin_inff();
        }
    }
    __syncthreads();

    float acc = 0.f;
    if (tid < D) {
        #pragma unroll
        for (int k = 0; k < KNN; k++) acc += emb[(size_t)selr[k] * D + tid];
    } else {
        int d = tid - D;
        #pragma unroll
        for (int k = 0; k < KNN; k++) acc += emb[(size_t)sele[k] * D + d];
    }
    catm_out[(size_t)bid * DM + tid] = acc * (1.f / KNN);
}

// ---------------- GEMM core (templated K), LDS passed in ----------------
#define BMT 128
#define BNT 128
#define BKT 64
#define LDP (BKT + 8)
#define GR  16

template<int KDIM>
__device__ __forceinline__ void gemm_core(
    const ushort* __restrict__ A, const ushort* __restrict__ B,
    ushort (*As)[LDP], ushort (*Bs)[LDP], int tid,
    int bm, int bn, int wm, int wn, int quad, int l16,
    floatx4 (&acc)[4][4])
{
    #pragma unroll
    for (int i = 0; i < 4; i++)
        #pragma unroll
        for (int j = 0; j < 4; j++) acc[i][j] = (floatx4){0.f, 0.f, 0.f, 0.f};
    for (int k0 = 0; k0 < KDIM; k0 += BKT) {
        __syncthreads();
        #pragma unroll
        for (int t = 0; t < 4; t++) {
            int chunk = tid + 256 * t;
            int r = chunk >> 3;
            int c8 = (chunk & 7) * 8;
            *(uint4*)&As[r][c8] = *(const uint4*)&A[(size_t)(bm * BMT + r) * KDIM + k0 + c8];
            *(uint4*)&Bs[r][c8] = *(const uint4*)&B[(size_t)(bn * BNT + r) * KDIM + k0 + c8];
        }
        __syncthreads();
        #pragma unroll
        for (int kk = 0; kk < BKT; kk += 32) {
            bf16x8 af[4], bf[4];
            #pragma unroll
            for (int i = 0; i < 4; i++)
                af[i] = *(const bf16x8*)&As[wm + i * 16 + l16][kk + quad * 8];
            #pragma unroll
            for (int j = 0; j < 4; j++)
                bf[j] = *(const bf16x8*)&Bs[wn + j * 16 + l16][kk + quad * 8];
            #pragma unroll
            for (int i = 0; i < 4; i++)
                #pragma unroll
                for (int j = 0; j < 4; j++)
                    acc[i][j] = __builtin_amdgcn_mfma_f32_16x16x32_bf16(
                        af[i], bf[j], acc[i][j], 0, 0, 0);
        }
    }
}

// ---------------- MEGA kernel: gcn -> se1 -> se2 -> ln -> sgw -> lstm x4 -> final ----------------
__global__ __launch_bounds__(256, 1) void mega_kernel(
    const float* __restrict__ catm, const float* __restrict__ gcn_W,
    const float* __restrict__ gcn_wb, const float* __restrict__ gcn_b,
    float* __restrict__ xf, ushort* __restrict__ xb,
    const ushort* __restrict__ w1_bf, const float* __restrict__ b1,
    ushort* __restrict__ t1_bf,
    const ushort* __restrict__ w2_bf, const float* __restrict__ b2,
    float* __restrict__ ys,
    const float* __restrict__ ln_g, const float* __restrict__ ln_b,
    float* __restrict__ ln_f, ushort* __restrict__ ln_bf,
    const float* __restrict__ W_hh, const float* __restrict__ b_ih,
    const float* __restrict__ b_hh,
    float* __restrict__ sg, float* __restrict__ gaddP,
    const ushort* __restrict__ wih_bf, const ushort* __restrict__ whh_bf,
    const float* __restrict__ bsumP,
    ushort* __restrict__ h_bfA, ushort* __restrict__ h_bfB,
    float* __restrict__ h_f, float* __restrict__ outp,
    unsigned* __restrict__ bar, unsigned* __restrict__ gen)
{
    __shared__ __align__(16) char smem[2 * BMT * LDP * 2];   // 36864 B, unioned
    ushort (*As)[LDP] = (ushort(*)[LDP])smem;
    ushort (*Bs)[LDP] = (ushort(*)[LDP])(smem + BMT * LDP * 2);

    int tid = threadIdx.x;
    int bid = blockIdx.x;
    int wave = tid >> 6, lane = tid & 63;
    int quad = lane >> 4, l16 = lane & 15;
    int wm = (wave >> 1) * 64, wn = (wave & 1) * 64;

    // ===== phase 0: gcn — 528 row-tiles of 16 =====
    {
        float (*cs)[DM] = (float(*)[DM])smem;                 // 16 KB
        float (*pp)[DM] = (float(*)[DM])(smem + GR * DM * 4); // 16 KB
        for (int t = bid; t < (BM2 * 2) / GR; t += NB) {
            int m0 = t * GR;
            #pragma unroll
            for (int tt = 0; tt < 4; tt++) {
                int chunk = tid + 256 * tt;
                int r = chunk >> 6, c4 = chunk & 63;
                *(float4*)&cs[r][c4 * 4] = *(const float4*)&catm[(size_t)(m0 + r) * DM + c4 * 4];
            }
            __syncthreads();
            int d = tid & 127, half = tid >> 7;
            float a[GR];
            #pragma unroll
            for (int r = 0; r < GR; r++) a[r] = 0.f;
            const float4* W4 = (const float4*)(gcn_W + (size_t)d * DM + half * D);
            for (int f4 = 0; f4 < D / 4; ++f4) {
                float4 w = W4[f4];
                #pragma unroll
                for (int r = 0; r < GR; r++) {
                    const float* c = &cs[r][half * D + f4 * 4];
                    a[r] += w.x * c[0] + w.y * c[1] + w.z * c[2] + w.w * c[3];
                }
            }
            #pragma unroll
            for (int r = 0; r < GR; r++) pp[r][tid] = a[r];
            __syncthreads();
            if (tid < D) {
                #pragma unroll
                for (int r = 0; r < GR; r++) {
                    float h = pp[r][tid] + pp[r][tid + D] + gcn_wb[tid] + gcn_b[tid];
                    float th = tanh_fast(h);
                    xf[(size_t)(m0 + r) * D + tid] = th;
                    xb[(size_t)(m0 + r) * D + tid] = f2bf(th);
                }
            }
            __syncthreads();   // protect cs reuse next iteration
        }
    }
    gsync(bar, gen);

    // ===== phase A: se_gemm1 — 33 x 4 = 132 tiles =====
    if (bid < 132) {
        int bm = bid % 33, bn = bid / 33;
        floatx4 acc[4][4];
        gemm_core<DM>(xb, w1_bf, As, Bs, tid, bm, bn, wm, wn, quad, l16, acc);
        #pragma unroll
        for (int i = 0; i < 4; i++)
            #pragma unroll
            for (int j = 0; j < 4; j++) {
                int row = bm * BMT + wm + i * 16 + quad * 4;
                int col = bn * BNT + wn + j * 16 + l16;
                float bb = b1[col];
                #pragma unroll
                for (int rr = 0; rr < 4; rr++)
                    t1_bf[(size_t)(row + rr) * DI + col] = f2bf(fmaxf(acc[i][j][rr] + bb, 0.f));
            }
    }
    gsync(bar, gen);

    // ===== phase B: se_gemm2 — 33 x 2 = 66 tiles =====
    if (bid < 66) {
        int bm = bid % 33, bn = bid / 33;
        floatx4 acc[4][4];
        gemm_core<DI>(t1_bf, w2_bf, As, Bs, tid, bm, bn, wm, wn, quad, l16, acc);
        #pragma unroll
        for (int i = 0; i < 4; i++)
            #pragma unroll
            for (int j = 0; j < 4; j++) {
                int row = bm * BMT + wm + i * 16 + quad * 4;
                int col = bn * BNT + wn + j * 16 + l16;
                float bb = b2[col];
                #pragma unroll
                for (int rr = 0; rr < 4; rr++)
                    ys[(size_t)(row + rr) * DM + col] =
                        acc[i][j][rr] + bb + xf[(size_t)(row + rr) * DM + col];
            }
    }
    gsync(bar, gen);

    // ===== phase C: LayerNorm — 528 groups of 8 rows =====
    for (int gidx = bid; gidx < BM2 / 8; gidx += NB) {
        int r = gidx * 8 + wave * 2;
        for (int rr = 0; rr < 2; ++rr, ++r) {
            float vals[4];
            float s = 0.f;
            #pragma unroll
            for (int e = 0; e < 4; e++) {
                vals[e] = ys[(size_t)r * DM + e * 64 + lane];
                s += vals[e];
            }
            #pragma unroll
            for (int off = 32; off; off >>= 1) s += __shfl_xor(s, off);
            float mu = s * (1.f / DM);
            float v = 0.f;
            #pragma unroll
            for (int e = 0; e < 4; e++) { float dd = vals[e] - mu; v += dd * dd; }
            #pragma unroll
            for (int off = 32; off; off >>= 1) v += __shfl_xor(v, off);
            float rstd = rsqrtf(v * (1.f / DM) + 1e-5f);
            #pragma unroll
            for (int e = 0; e < 4; e++) {
                int dd = e * 64 + lane;
                float ov = (vals[e] - mu) * rstd * ln_g[dd] + ln_b[dd];
                ln_f[(size_t)r * DM + dd] = ov;
                ln_bf[(size_t)r * DM + dd] = f2bf(ov);
            }
        }
    }
    gsync(bar, gen);

    // ===== phase D: sg mean + gaddP (blocks 0..3) =====
    if (bid < 4) {
        float* s = (float*)smem;
        float a = 0.f;
        for (int r = 0; r < BS; r++) a += ln_f[(size_t)(BQ + r) * DM + tid];
        a *= (1.f / BS);
        s[tid] = a;
        if (bid == 0) sg[tid] = a;
        __syncthreads();
        int idx = bid * 256 + tid;
        int g = idx >> 8, u = idx & 255;
        int oldrow = g * 512 + u;
        const float4* w4 = (const float4*)(W_hh + (size_t)oldrow * HH + DM);
        float acc = 0.f;
        for (int f4 = 0; f4 < DM / 4; ++f4) {
            float4 w = w4[f4];
            acc += w.x * s[f4 * 4] + w.y * s[f4 * 4 + 1] + w.z * s[f4 * 4 + 2] + w.w * s[f4 * 4 + 3];
        }
        float bs = b_ih[oldrow] + b_hh[oldrow];
        int n = (u >> 5) * 128 + ((u >> 4) & 1) * 64 + g * 16 + (u & 15);
        gaddP[n] = bs + acc;
    }
    gsync(bar, gen);

    // ===== phases E..H: LSTM — block owns tile (bm, bn) for all 4 steps =====
    // P0 (64 VGPRs) and c (16 VGPRs) persist in registers across steps.
    {
        int bm = bid >> 3, bn = bid & 7;
        int u = bn * 32 + (wn ? 16 : 0) + l16;

        floatx4 P0[4][4];
        floatx4 cfr[4];
        float b4[4], g4[4];
        #pragma unroll
        for (int j = 0; j < 4; j++) {
            b4[j] = bsumP[bn * 128 + wn + j * 16 + l16];
            g4[j] = gaddP[bn * 128 + wn + j * 16 + l16];
        }

        // step 1: gates = ln @ wih^T (+bsum); c = sig(i)*tanh(g); h = ln + sig(o)*tanh(c)
        {
            floatx4 acc[4][4];
            gemm_core<GK>(ln_bf, wih_bf, As, Bs, tid, bm, bn, wm, wn, quad, l16, acc);
            #pragma unroll
            for (int i = 0; i < 4; i++) {
                int row = bm * BMT + wm + i * 16 + quad * 4;
                #pragma unroll
                for (int j = 0; j < 4; j++) P0[i][j] = acc[i][j];
                #pragma unroll
                for (int rr = 0; rr < 4; rr++) {
                    float iv = acc[i][0][rr] + b4[0];
                    float gv = acc[i][2][rr] + b4[2];
                    float ov = acc[i][3][rr] + b4[3];
                    float cv = sigmoidf_(iv) * tanh_fast(gv);
                    cfr[i][rr] = cv;
                    float h = ln_f[(size_t)(row + rr) * DM + u] + sigmoidf_(ov) * tanh_fast(cv);
                    h_bfA[(size_t)(row + rr) * DM + u] = f2bf(h);
                }
            }
        }
        gsync(bar, gen);

        // steps 2..4
        const ushort* hin = h_bfA;
        ushort* hout = h_bfB;
        for (int step = 0; step < 3; step++) {
            int last = (step == 2);
            floatx4 acc[4][4];
            gemm_core<GK>(hin, whh_bf, As, Bs, tid, bm, bn, wm, wn, quad, l16, acc);
            #pragma unroll
            for (int i = 0; i < 4; i++) {
                int row = bm * BMT + wm + i * 16 + quad * 4;
                #pragma unroll
                for (int rr = 0; rr < 4; rr++) {
                    float iv = acc[i][0][rr] + P0[i][0][rr] + g4[0];
                    float fv = acc[i][1][rr] + P0[i][1][rr] + g4[1];
                    float gv = acc[i][2][rr] + P0[i][2][rr] + g4[2];
                    float ov = acc[i][3][rr] + P0[i][3][rr] + g4[3];
                    float cv = sigmoidf_(fv) * cfr[i][rr] + sigmoidf_(iv) * tanh_fast(gv);
                    cfr[i][rr] = cv;
                    float h = ln_f[(size_t)(row + rr) * DM + u] + sigmoidf_(ov) * tanh_fast(cv);
                    if (last) h_f[(size_t)(row + rr) * DM + u] = h;
                    else      hout[(size_t)(row + rr) * DM + u] = f2bf(h);
                }
            }
            gsync(bar, gen);
            const ushort* tmp = hin; hin = hout; hout = (ushort*)tmp;
        }
    }

    // ===== phase I: final cosine — 16 rows per block =====
    {
        float* sgs = (float*)smem;
        sgs[tid] = sg[tid];
        __syncthreads();
        float sn = 0.f;
        #pragma unroll
        for (int e = 0; e < 4; e++) { float v = sgs[e * 64 + lane]; sn += v * v; }
        #pragma unroll
        for (int off = 32; off; off >>= 1) sn += __shfl_xor(sn, off);
        float sgnorm = fmaxf(sqrtf(sn), 1e-12f);
        for (int it = 0; it < 4; it++) {
            int row = bid * 16 + it * 4 + wave;
            const float* h = h_f + (size_t)row * DM;
            float dot = 0.f, hn = 0.f;
            #pragma unroll
            for (int e = 0; e < 4; e++) {
                float hv = h[e * 64 + lane];
                dot += hv * sgs[e * 64 + lane];
                hn += hv * hv;
            }
            #pragma unroll
            for (int off = 32; off; off >>= 1) { dot += __shfl_xor(dot, off); hn += __shfl_xor(hn, off); }
            if (lane == 0) outp[row] = dot / (fmaxf(sqrtf(hn), 1e-12f) * sgnorm);
        }
    }
}

extern "C" void kernel_launch(void* const* d_in, const int* in_sizes, int n_in,
                              void* d_out, int out_size, void* d_ws, size_t ws_size,
                              hipStream_t stream)
{
    const int* query    = (const int*)d_in[0];
    const int* support  = (const int*)d_in[1];
    const int* q_l_conn = (const int*)d_in[2];
    const int* q_r_conn = (const int*)d_in[4];
    const int* s_l_conn = (const int*)d_in[6];
    const int* s_r_conn = (const int*)d_in[8];
    const float* emb    = (const float*)d_in[10];
    const float* gcn_W  = (const float*)d_in[11];
    const float* gcn_wb = (const float*)d_in[12];
    const float* gcn_b  = (const float*)d_in[13];
    const float* se_w1  = (const float*)d_in[14];
    const float* se_b1  = (const float*)d_in[15];
    const float* se_w2  = (const float*)d_in[16];
    const float* se_b2  = (const float*)d_in[17];
    const float* ln_g   = (const float*)d_in[18];
    const float* ln_b   = (const float*)d_in[19];
    const float* W_ih   = (const float*)d_in[20];
    const float* W_hh   = (const float*)d_in[21];
    const float* b_ih   = (const float*)d_in[22];
    const float* b_hh   = (const float*)d_in[23];
    float* out = (float*)d_out;

    char* wsb = (char*)d_ws;
    float*  catm   = (float*)wsb;  wsb += (size_t)(BM2 * 2) * DM * 4;
    float*  xf     = (float*)wsb;  wsb += (size_t)BM2 * DM * 4;
    ushort* xb     = (ushort*)wsb; wsb += (size_t)BM2 * DM * 2;
    ushort* t1_bf  = (ushort*)wsb; wsb += (size_t)BM2 * DI * 2;
    float*  ys     = (float*)wsb;  wsb += (size_t)BM2 * DM * 4;
    float*  ln_f   = (float*)wsb;  wsb += (size_t)BM2 * DM * 4;
    ushort* ln_bf  = (ushort*)wsb; wsb += (size_t)BM2 * DM * 2;
    float*  sg     = (float*)wsb;  wsb += DM * 4;
    float*  bsumP  = (float*)wsb;  wsb += G2 * 4;
    float*  gaddP  = (float*)wsb;  wsb += G2 * 4;
    ushort* wih_bf = (ushort*)wsb; wsb += (size_t)G2 * DM * 2;
    ushort* whh_bf = (ushort*)wsb; wsb += (size_t)G2 * DM * 2;
    ushort* w1_bf  = (ushort*)wsb; wsb += (size_t)DI * DM * 2;
    ushort* w2_bf  = (ushort*)wsb; wsb += (size_t)DM * DI * 2;
    float*  norms  = (float*)wsb;  wsb += (size_t)NSYM * 4;
    ushort* h_bfA  = (ushort*)wsb; wsb += (size_t)BQ * DM * 2;
    ushort* h_bfB  = (ushort*)wsb; wsb += (size_t)BQ * DM * 2;
    float*  h_f    = (float*)wsb;  wsb += (size_t)BQ * DM * 4;
    unsigned* bar  = (unsigned*)wsb; wsb += 256;   // barrier state, own cacheline
    unsigned* gen  = (unsigned*)(wsb); wsb += 256;

    prep_kernel<<<50000 + G2 + 512, 256, 0, stream>>>(
        emb, norms, W_ih, W_hh, b_ih, b_hh, se_w1, se_w2,
        wih_bf, whh_bf, bsumP, w1_bf, w2_bf, bar, gen);
    ne_kernel<<<BQ * 2 + BS * 2, 256, 0, stream>>>(
        q_l_conn, q_r_conn, query, s_l_conn, s_r_conn, support,
        emb, norms, catm);
    mega_kernel<<<NB, 256, 0, stream>>>(
        catm, gcn_W, gcn_wb, gcn_b, xf, xb,
        w1_bf, se_b1, t1_bf, w2_bf, se_b2, ys,
        ln_g, ln_b, ln_f, ln_bf,
        W_hh, b_ih, b_hh, sg, gaddP,
        wih_bf, whh_bf, bsumP,
        h_bfA, h_bfB, h_f, out, bar, gen);
}